// Round 4
// baseline (1005.561 us; speedup 1.0000x reference)
//
#include <hip/hip_runtime.h>
#include <hip/hip_bf16.h>

#define N_NODES 50000
#define N_EDGES 800000
#define HDIM 128
#define NCH 5
#define NB_SCAN ((N_NODES + 255) / 256)  // 196
#define NB_E (N_EDGES / 256)             // 3125 (exact)
#define CUTOFF 10.0f

typedef float f4 __attribute__((ext_vector_type(4)));
typedef short bf8 __attribute__((ext_vector_type(8)));    // 8 bf16 = MFMA A/B frag
typedef float f32x4 __attribute__((ext_vector_type(4)));  // MFMA C/D frag

struct __align__(8) b16x4 { __hip_bfloat16 v[4]; };
struct __align__(16) b16x8 { __hip_bfloat16 v[8]; };

// ---------------- CSR build ----------------

__global__ void k_count(const int* __restrict__ dst, int* __restrict__ cnt) {
  int i = blockIdx.x * blockDim.x + threadIdx.x;
  if (i < N_EDGES) atomicAdd(&cnt[dst[i]], 1);
}

__global__ __launch_bounds__(256) void k_scan_local(const int* __restrict__ cnt,
                                                    int* __restrict__ row,
                                                    int* __restrict__ bsum) {
  __shared__ int buf[256];
  int b = blockIdx.x, tid = threadIdx.x, i = b * 256 + tid;
  int v = (i < N_NODES) ? cnt[i] : 0;
  buf[tid] = v;
  __syncthreads();
  for (int off = 1; off < 256; off <<= 1) {
    int t = (tid >= off) ? buf[tid - off] : 0;
    __syncthreads();
    buf[tid] += t;
    __syncthreads();
  }
  if (i < N_NODES) row[i] = buf[tid] - v;  // local exclusive
  if (tid == 255) bsum[b] = buf[255];
}

__global__ __launch_bounds__(256) void k_scan_top(const int* __restrict__ bsum,
                                                  int* __restrict__ boff) {
  __shared__ int buf[256];
  int tid = threadIdx.x;
  int v = (tid < NB_SCAN) ? bsum[tid] : 0;
  buf[tid] = v;
  __syncthreads();
  for (int off = 1; off < 256; off <<= 1) {
    int t = (tid >= off) ? buf[tid - off] : 0;
    __syncthreads();
    buf[tid] += t;
    __syncthreads();
  }
  if (tid < NB_SCAN) boff[tid] = buf[tid] - v;
  if (tid == 255) boff[NB_SCAN] = buf[255];
}

__global__ __launch_bounds__(256) void k_scan_add(int* __restrict__ row,
                                                  const int* __restrict__ boff,
                                                  int* __restrict__ cur) {
  int b = blockIdx.x, tid = threadIdx.x, i = b * 256 + tid;
  if (i < N_NODES) {
    int r = row[i] + boff[b];
    row[i] = r;
    cur[i] = r;
  }
  if (b == 0 && tid == 0) row[N_NODES] = boff[NB_SCAN];
}

// pos[e] = CSR slot of edge e; esrc[slot] = src | (mask<<31)
__global__ void k_scatter(const int* __restrict__ src, const int* __restrict__ dst,
                          const float* __restrict__ elen, int* __restrict__ cur,
                          int* __restrict__ pos, int* __restrict__ esrc) {
  int i = blockIdx.x * blockDim.x + threadIdx.x;
  if (i < N_EDGES) {
    int d = dst[i];
    int p = atomicAdd(&cur[d], 1);
    pos[i] = p;
    int m = (elen[i] <= CUTOFF) ? (int)0x80000000 : 0;
    esrc[p] = src[i] | m;
  }
}

// ---------------- edge compaction (unmasked edges only), deterministic --------

__global__ __launch_bounds__(256) void k_escan_local(const float* __restrict__ elen,
                                                     int* __restrict__ eloc,
                                                     int* __restrict__ ebsum) {
  __shared__ int buf[256];
  int b = blockIdx.x, tid = threadIdx.x, i = b * 256 + tid;
  int v = (elen[i] <= CUTOFF) ? 1 : 0;
  buf[tid] = v;
  __syncthreads();
  for (int off = 1; off < 256; off <<= 1) {
    int t = (tid >= off) ? buf[tid - off] : 0;
    __syncthreads();
    buf[tid] += t;
    __syncthreads();
  }
  eloc[i] = buf[tid] - v;
  if (tid == 255) ebsum[b] = buf[255];
}

__global__ __launch_bounds__(256) void k_escan_top(const int* __restrict__ ebsum,
                                                   int* __restrict__ eboff) {
  __shared__ int buf[256];
  int tid = threadIdx.x;
  int run = 0;
  for (int base = 0; base < NB_E; base += 256) {
    int i = base + tid;
    int v = (i < NB_E) ? ebsum[i] : 0;
    buf[tid] = v;
    __syncthreads();
    for (int off = 1; off < 256; off <<= 1) {
      int t = (tid >= off) ? buf[tid - off] : 0;
      __syncthreads();
      buf[tid] += t;
      __syncthreads();
    }
    if (i < NB_E) eboff[i] = run + buf[tid] - v;
    run += buf[255];
    __syncthreads();
  }
  if (tid == 0) eboff[NB_E] = run;  // nUnmasked
}

__global__ __launch_bounds__(256) void k_ecompact(const float* __restrict__ elen,
                                                  const int* __restrict__ eloc,
                                                  const int* __restrict__ eboff,
                                                  int* __restrict__ elist) {
  int b = blockIdx.x, i = b * 256 + threadIdx.x;
  if (elen[i] <= CUTOFF) elist[eboff[b] + eloc[i]] = i;
}

// ---------------- weight repack for MFMA B-fragments ----------------
// wp[((jt*4+kk)*64 + l)*8 + j] = bf16( w[(kk*32 + (l>>4)*8 + j)*128 + jt*16 + (l&15)] )

__global__ __launch_bounds__(256) void k_repack(const float* __restrict__ w,
                                                __hip_bfloat16* __restrict__ wp) {
  int idx = blockIdx.x * 256 + threadIdx.x;
  int l = idx & 63;
  int f = idx >> 6;
  int kk = f & 3, jt = f >> 2;
  int col = jt * 16 + (l & 15);
  int kb = kk * 32 + (l >> 4) * 8;
  b16x8 o;
#pragma unroll
  for (int j = 0; j < 8; ++j) o.v[j] = __float2bfloat16(w[(kb + j) * HDIM + col]);
  *reinterpret_cast<b16x8*>(&wp[idx * 8]) = o;
}

// ---------------- f32 4x4-tile GEMM (node_emb only) --------

__device__ __forceinline__ void tile_gemm(const float (*in)[129],
                                          const float* __restrict__ wmat,
                                          const float* __restrict__ bias,
                                          int r4, int jb, float acc[4][4]) {
  f4 bv = *reinterpret_cast<const f4*>(&bias[jb]);
#pragma unroll
  for (int ii = 0; ii < 4; ++ii)
#pragma unroll
    for (int jj = 0; jj < 4; ++jj) acc[ii][jj] = bv[jj];
#pragma unroll 4
  for (int k = 0; k < HDIM; ++k) {
    f4 wv = *reinterpret_cast<const f4*>(&wmat[k * HDIM + jb]);
    float a0 = in[r4 + 0][k];
    float a1 = in[r4 + 1][k];
    float a2 = in[r4 + 2][k];
    float a3 = in[r4 + 3][k];
#pragma unroll
    for (int jj = 0; jj < 4; ++jj) {
      acc[0][jj] += a0 * wv[jj];
      acc[1][jj] += a1 * wv[jj];
      acc[2][jj] += a2 * wv[jj];
      acc[3][jj] += a3 * wv[jj];
    }
  }
}

// ---------------- node embedding -> hA ----------------

__global__ __launch_bounds__(256) void k_node_emb(
    const float* __restrict__ z, const float* __restrict__ w0a,
    const float* __restrict__ b0a, const float* __restrict__ w0b,
    const float* __restrict__ b0b, float* __restrict__ h) {
  __shared__ float zs[32][NCH];
  __shared__ float w0as[NCH][HDIM];
  __shared__ float hs[32][129];
  int tid = threadIdx.x;
  int r0 = blockIdx.x * 32;

  for (int i = tid; i < NCH * HDIM; i += 256) w0as[i / HDIM][i % HDIM] = w0a[i];
  for (int i = tid; i < 32 * NCH; i += 256) {
    int r = i / NCH, c = i % NCH;
    int gr = r0 + r;
    zs[r][c] = (gr < N_NODES) ? z[gr * NCH + c] : 0.f;
  }
  __syncthreads();

  for (int i = tid; i < 32 * HDIM; i += 256) {
    int j = i & (HDIM - 1), r = i >> 7;
    float a = b0a[j];
#pragma unroll
    for (int c = 0; c < NCH; ++c) a += zs[r][c] * w0as[c][j];
    hs[r][j] = fmaxf(a, 0.f);
  }
  __syncthreads();

  int cg = tid & 31, rg = tid >> 5;
  int jb = cg * 4, r4 = rg * 4;
  float acc[4][4];
  tile_gemm(hs, w0b, b0b, r4, jb, acc);

#pragma unroll
  for (int ii = 0; ii < 4; ++ii) {
    int gr = r0 + r4 + ii;
    if (gr < N_NODES) {
      f4 o = {acc[ii][0], acc[ii][1], acc[ii][2], acc[ii][3]};
      *reinterpret_cast<f4*>(&h[(size_t)gr * HDIM + jb]) = o;
    }
  }
}

// ---------------- edge gate via MFMA over COMPACTED edge list ------------------
// Block = 256 thr = 4 waves, 64 unmasked edges. Stores to CSR slot pos[e].

#define SWZ(row, colByte) ((row) * 256 + ((colByte) ^ (((row) & 7) << 4)))

__global__ __launch_bounds__(256) void k_edge_gate_mfma(
    const float* __restrict__ attr, const __hip_bfloat16* __restrict__ w2aP,
    const float* __restrict__ b2a, const __hip_bfloat16* __restrict__ w2bP,
    const float* __restrict__ b2b, const int* __restrict__ elist,
    const int* __restrict__ nUmPtr, const int* __restrict__ pos,
    __hip_bfloat16* __restrict__ Wp) {
  __shared__ char sA[64 * 256];  // 64 x 128 bf16, swizzled
  __shared__ char sH[64 * 256];
  __shared__ int sPos[64];
  __shared__ int sEid[64];
  const int tid = threadIdx.x;
  const int wv = tid >> 6, l = tid & 63;
  const int e0 = blockIdx.x * 64;
  const int nUm = nUmPtr[0];
  if (e0 >= nUm) return;

  if (tid < 64) {
    int idx = e0 + tid;
    int e = elist[(idx < nUm) ? idx : (nUm - 1)];
    sEid[tid] = e;
    sPos[tid] = pos[e];
  }
  __syncthreads();

  // stage attr rows (gathered by edge id) -> sA bf16
#pragma unroll
  for (int i = 0; i < 8; ++i) {
    int c = tid + i * 256;
    int row = c >> 5, col4 = (c & 31) * 4;
    f4 v = *reinterpret_cast<const f4*>(&attr[(size_t)sEid[row] * HDIM + col4]);
    b16x4 o;
    o.v[0] = __float2bfloat16(v[0]);
    o.v[1] = __float2bfloat16(v[1]);
    o.v[2] = __float2bfloat16(v[2]);
    o.v[3] = __float2bfloat16(v[3]);
    *reinterpret_cast<b16x4*>(&sA[SWZ(row, col4 * 2)]) = o;
  }

  bf8 B1[2][4], B2[2][4];
#pragma unroll
  for (int nt = 0; nt < 2; ++nt)
#pragma unroll
    for (int kk = 0; kk < 4; ++kk) {
      int f = (2 * wv + nt) * 4 + kk;
      B1[nt][kk] = *reinterpret_cast<const bf8*>(&w2aP[(f * 64 + l) * 8]);
      B2[nt][kk] = *reinterpret_cast<const bf8*>(&w2bP[(f * 64 + l) * 8]);
    }

  __syncthreads();

  // layer 1
  f32x4 acc[4][2];
  float bias[2];
#pragma unroll
  for (int nt = 0; nt < 2; ++nt) bias[nt] = b2a[(2 * wv + nt) * 16 + (l & 15)];
#pragma unroll
  for (int mt = 0; mt < 4; ++mt)
#pragma unroll
    for (int nt = 0; nt < 2; ++nt)
      acc[mt][nt] = (f32x4){bias[nt], bias[nt], bias[nt], bias[nt]};

#pragma unroll
  for (int kk = 0; kk < 4; ++kk)
#pragma unroll
    for (int mt = 0; mt < 4; ++mt) {
      int row = mt * 16 + (l & 15);
      int kByte = (kk * 32 + (l >> 4) * 8) * 2;
      bf8 a = *reinterpret_cast<const bf8*>(&sA[SWZ(row, kByte)]);
#pragma unroll
      for (int nt = 0; nt < 2; ++nt)
        acc[mt][nt] = __builtin_amdgcn_mfma_f32_16x16x32_bf16(a, B1[nt][kk],
                                                              acc[mt][nt], 0, 0, 0);
    }

#pragma unroll
  for (int mt = 0; mt < 4; ++mt)
#pragma unroll
    for (int nt = 0; nt < 2; ++nt) {
      int colb = ((2 * wv + nt) * 16 + (l & 15)) * 2;
#pragma unroll
      for (int i = 0; i < 4; ++i) {
        int row = mt * 16 + (l >> 4) * 4 + i;
        *reinterpret_cast<__hip_bfloat16*>(&sH[SWZ(row, colb)]) =
            __float2bfloat16(fmaxf(acc[mt][nt][i], 0.f));
      }
    }
  __syncthreads();

  // layer 2
#pragma unroll
  for (int nt = 0; nt < 2; ++nt) bias[nt] = b2b[(2 * wv + nt) * 16 + (l & 15)];
#pragma unroll
  for (int mt = 0; mt < 4; ++mt)
#pragma unroll
    for (int nt = 0; nt < 2; ++nt)
      acc[mt][nt] = (f32x4){bias[nt], bias[nt], bias[nt], bias[nt]};

#pragma unroll
  for (int kk = 0; kk < 4; ++kk)
#pragma unroll
    for (int mt = 0; mt < 4; ++mt) {
      int row = mt * 16 + (l & 15);
      int kByte = (kk * 32 + (l >> 4) * 8) * 2;
      bf8 a = *reinterpret_cast<const bf8*>(&sH[SWZ(row, kByte)]);
#pragma unroll
      for (int nt = 0; nt < 2; ++nt)
        acc[mt][nt] = __builtin_amdgcn_mfma_f32_16x16x32_bf16(a, B2[nt][kk],
                                                              acc[mt][nt], 0, 0, 0);
    }

  // no mask needed (all listed edges pass cutoff); write bf16 to sA
#pragma unroll
  for (int mt = 0; mt < 4; ++mt)
#pragma unroll
    for (int nt = 0; nt < 2; ++nt) {
      int colb = ((2 * wv + nt) * 16 + (l & 15)) * 2;
#pragma unroll
      for (int i = 0; i < 4; ++i) {
        int row = mt * 16 + (l >> 4) * 4 + i;
        *reinterpret_cast<__hip_bfloat16*>(&sA[SWZ(row, colb)]) =
            __float2bfloat16(acc[mt][nt][i]);
      }
    }
  __syncthreads();

  // store rows to CSR slots (256 B contiguous per row), tail-guarded
#pragma unroll
  for (int i = 0; i < 4; ++i) {
    int c = tid + i * 256;
    int row = c >> 4, colc = c & 15;
    if (e0 + row < nUm) {
      b16x8 v = *reinterpret_cast<const b16x8*>(&sA[SWZ(row, colc * 16)]);
      *reinterpret_cast<b16x8*>(&Wp[(size_t)sPos[row] * HDIM + colc * 8]) = v;
    }
  }
}

// ---------------- fused conv: aggregate + update-MLP (MFMA) --------------------
// h_out[n] = h_in[n] + act(MLP1( sum_{p in CSR[n]} relu(h_in[esrc]+W) + h_in[n] ))
// Block = 256 thr = 4 waves = 8 half-wave groups, 64 nodes.

__global__ __launch_bounds__(256) void k_conv(
    const float* __restrict__ h_in, float* __restrict__ h_out,
    const __hip_bfloat16* __restrict__ Wp, const int* __restrict__ row,
    const int* __restrict__ esrc, const __hip_bfloat16* __restrict__ w1aP,
    const float* __restrict__ b1a, const __hip_bfloat16* __restrict__ w1bP,
    const float* __restrict__ b1b, int relu_out) {
  __shared__ char sA[64 * 256];  // 64 x 128 bf16 (agg + h), swizzled
  __shared__ char sH[64 * 256];
  const int tid = threadIdx.x;
  const int wv = tid >> 6, l = tid & 63;
  const int r0 = blockIdx.x * 64;

  // B-frags first (independent; hides under phase A)
  bf8 B1[2][4], B2[2][4];
#pragma unroll
  for (int nt = 0; nt < 2; ++nt)
#pragma unroll
    for (int kk = 0; kk < 4; ++kk) {
      int f = (2 * wv + nt) * 4 + kk;
      B1[nt][kk] = *reinterpret_cast<const bf8*>(&w1aP[(f * 64 + l) * 8]);
      B2[nt][kk] = *reinterpret_cast<const bf8*>(&w1bP[(f * 64 + l) * 8]);
    }

  // ---- phase A: aggregation, 8 nodes in flight (one per 32-lane group)
  const int g = tid >> 5;          // 0..7
  const int c4 = (tid & 31) * 4;   // 4 f32 cols per lane
#pragma unroll
  for (int rr = 0; rr < 8; ++rr) {
    int r = rr * 8 + g;
    int n = r0 + r;
    f4 s = {0.f, 0.f, 0.f, 0.f};
    if (n < N_NODES) {
      int beg = row[n], end = row[n + 1];
      for (int p = beg; p < end; ++p) {
        int sv = esrc[p];
        int sr = sv & 0x7fffffff;
        f4 hv = *reinterpret_cast<const f4*>(&h_in[(size_t)sr * HDIM + c4]);
        if (sv < 0) {  // unmasked: W row exists
          b16x4 wv = *reinterpret_cast<const b16x4*>(&Wp[(size_t)p * HDIM + c4]);
#pragma unroll
          for (int q = 0; q < 4; ++q)
            s[q] += fmaxf(hv[q] + __bfloat162float(wv.v[q]), 0.f);
        } else {
#pragma unroll
          for (int q = 0; q < 4; ++q) s[q] += fmaxf(hv[q], 0.f);
        }
      }
      f4 hh = *reinterpret_cast<const f4*>(&h_in[(size_t)n * HDIM + c4]);
      s += hh;  // (1+eps)*h, eps = 0
    }
    b16x4 o;
    o.v[0] = __float2bfloat16(s[0]);
    o.v[1] = __float2bfloat16(s[1]);
    o.v[2] = __float2bfloat16(s[2]);
    o.v[3] = __float2bfloat16(s[3]);
    *reinterpret_cast<b16x4*>(&sA[SWZ(r, c4 * 2)]) = o;
  }
  __syncthreads();

  // ---- phase B: update MLP
  f32x4 acc[4][2];
  float bias[2];
#pragma unroll
  for (int nt = 0; nt < 2; ++nt) bias[nt] = b1a[(2 * wv + nt) * 16 + (l & 15)];
#pragma unroll
  for (int mt = 0; mt < 4; ++mt)
#pragma unroll
    for (int nt = 0; nt < 2; ++nt)
      acc[mt][nt] = (f32x4){bias[nt], bias[nt], bias[nt], bias[nt]};

#pragma unroll
  for (int kk = 0; kk < 4; ++kk)
#pragma unroll
    for (int mt = 0; mt < 4; ++mt) {
      int rowi = mt * 16 + (l & 15);
      int kByte = (kk * 32 + (l >> 4) * 8) * 2;
      bf8 a = *reinterpret_cast<const bf8*>(&sA[SWZ(rowi, kByte)]);
#pragma unroll
      for (int nt = 0; nt < 2; ++nt)
        acc[mt][nt] = __builtin_amdgcn_mfma_f32_16x16x32_bf16(a, B1[nt][kk],
                                                              acc[mt][nt], 0, 0, 0);
    }

#pragma unroll
  for (int mt = 0; mt < 4; ++mt)
#pragma unroll
    for (int nt = 0; nt < 2; ++nt) {
      int colb = ((2 * wv + nt) * 16 + (l & 15)) * 2;
#pragma unroll
      for (int i = 0; i < 4; ++i) {
        int rowi = mt * 16 + (l >> 4) * 4 + i;
        *reinterpret_cast<__hip_bfloat16*>(&sH[SWZ(rowi, colb)]) =
            __float2bfloat16(fmaxf(acc[mt][nt][i], 0.f));
      }
    }
  __syncthreads();

#pragma unroll
  for (int nt = 0; nt < 2; ++nt) bias[nt] = b1b[(2 * wv + nt) * 16 + (l & 15)];
#pragma unroll
  for (int mt = 0; mt < 4; ++mt)
#pragma unroll
    for (int nt = 0; nt < 2; ++nt)
      acc[mt][nt] = (f32x4){bias[nt], bias[nt], bias[nt], bias[nt]};

#pragma unroll
  for (int kk = 0; kk < 4; ++kk)
#pragma unroll
    for (int mt = 0; mt < 4; ++mt) {
      int rowi = mt * 16 + (l & 15);
      int kByte = (kk * 32 + (l >> 4) * 8) * 2;
      bf8 a = *reinterpret_cast<const bf8*>(&sH[SWZ(rowi, kByte)]);
#pragma unroll
      for (int nt = 0; nt < 2; ++nt)
        acc[mt][nt] = __builtin_amdgcn_mfma_f32_16x16x32_bf16(a, B2[nt][kk],
                                                              acc[mt][nt], 0, 0, 0);
    }

  // epilogue: h_out = h_in + act(out)
#pragma unroll
  for (int mt = 0; mt < 4; ++mt)
#pragma unroll
    for (int nt = 0; nt < 2; ++nt) {
      int col = (2 * wv + nt) * 16 + (l & 15);
#pragma unroll
      for (int i = 0; i < 4; ++i) {
        int rowi = mt * 16 + (l >> 4) * 4 + i;
        int gr = r0 + rowi;
        if (gr < N_NODES) {
          float t = acc[mt][nt][i];
          if (relu_out) t = fmaxf(t, 0.f);
          size_t idx = (size_t)gr * HDIM + col;
          h_out[idx] = h_in[idx] + t;
        }
      }
    }
}

// ---------------- launch --------------------------------------------------------

extern "C" void kernel_launch(void* const* d_in, const int* in_sizes, int n_in,
                              void* d_out, int out_size, void* d_ws, size_t ws_size,
                              hipStream_t stream) {
  const float* z = (const float*)d_in[0];
  const int* ei = (const int*)d_in[1];
  const float* attr = (const float*)d_in[2];
  const float* elen = (const float*)d_in[3];
  const float* w0a = (const float*)d_in[4];
  const float* b0a = (const float*)d_in[5];
  const float* w0b = (const float*)d_in[6];
  const float* b0b = (const float*)d_in[7];
  const float* w1a = (const float*)d_in[8];
  const float* b1a = (const float*)d_in[9];
  const float* w1b = (const float*)d_in[10];
  const float* b1b = (const float*)d_in[11];
  const float* w2a = (const float*)d_in[12];
  const float* b2a = (const float*)d_in[13];
  const float* w2b = (const float*)d_in[14];
  const float* b2b = (const float*)d_in[15];

  float* hO = (float*)d_out;  // ping-pong buffer B (holds final result)

  char* ws = (char*)d_ws;
  size_t off = 0;
  __hip_bfloat16* Wp = (__hip_bfloat16*)(ws + off);
  off += (size_t)N_EDGES * HDIM * 2;  // 204.8 MB
  float* hA = (float*)(ws + off);     // ping-pong buffer A
  int* eloc = (int*)(ws + off);       // aliases hA: consumed before node_emb runs
  off += (size_t)N_NODES * HDIM * 4;  // 25.6 MB
  int* row = (int*)(ws + off);
  off += (size_t)(N_NODES + 64) * 4;
  int* cnt = (int*)(ws + off);
  off += (size_t)N_NODES * 4;
  int* cur = (int*)(ws + off);
  off += (size_t)N_NODES * 4;
  int* pos = (int*)(ws + off);
  off += (size_t)N_EDGES * 4;
  int* esrc = (int*)(ws + off);
  off += (size_t)N_EDGES * 4;
  int* elist = (int*)(ws + off);
  off += (size_t)N_EDGES * 4;
  int* bsum = (int*)(ws + off);
  off += (size_t)(NB_SCAN + 8) * 4;
  int* boff = (int*)(ws + off);
  off += (size_t)(NB_SCAN + 8) * 4;
  int* ebsum = (int*)(ws + off);
  off += (size_t)(NB_E + 8) * 4;
  int* eboff = (int*)(ws + off);
  off += (size_t)(NB_E + 8) * 4;
  __hip_bfloat16* w2aP = (__hip_bfloat16*)(ws + off);
  off += (size_t)HDIM * HDIM * 2;
  __hip_bfloat16* w2bP = (__hip_bfloat16*)(ws + off);
  off += (size_t)HDIM * HDIM * 2;
  __hip_bfloat16* w1aP = (__hip_bfloat16*)(ws + off);
  off += (size_t)HDIM * HDIM * 2;
  __hip_bfloat16* w1bP = (__hip_bfloat16*)(ws + off);
  off += (size_t)HDIM * HDIM * 2;  // total ~241 MB

  const int* src = ei;
  const int* dst = ei + N_EDGES;

  // CSR build
  hipMemsetAsync(cnt, 0, (size_t)N_NODES * 4, stream);
  k_count<<<(N_EDGES + 255) / 256, 256, 0, stream>>>(dst, cnt);
  k_scan_local<<<NB_SCAN, 256, 0, stream>>>(cnt, row, bsum);
  k_scan_top<<<1, 256, 0, stream>>>(bsum, boff);
  k_scan_add<<<NB_SCAN, 256, 0, stream>>>(row, boff, cur);
  k_scatter<<<(N_EDGES + 255) / 256, 256, 0, stream>>>(src, dst, elen, cur, pos,
                                                       esrc);

  // edge compaction (uses eloc, which aliases hA — completes before node_emb)
  k_escan_local<<<NB_E, 256, 0, stream>>>(elen, eloc, ebsum);
  k_escan_top<<<1, 256, 0, stream>>>(ebsum, eboff);
  k_ecompact<<<NB_E, 256, 0, stream>>>(elen, eloc, eboff, elist);

  // weight repacks
  k_repack<<<8, 256, 0, stream>>>(w2a, w2aP);
  k_repack<<<8, 256, 0, stream>>>(w2b, w2bP);
  k_repack<<<8, 256, 0, stream>>>(w1a, w1aP);
  k_repack<<<8, 256, 0, stream>>>(w1b, w1bP);

  // node embedding -> hA
  k_node_emb<<<(N_NODES + 31) / 32, 256, 0, stream>>>(z, w0a, b0a, w0b, b0b, hA);

  // edge gate over compacted list (worst-case grid; blocks past nUm exit early)
  k_edge_gate_mfma<<<N_EDGES / 64, 256, 0, stream>>>(attr, w2aP, b2a, w2bP, b2b,
                                                     elist, eboff + NB_E, pos, Wp);

  // convs with ping-pong: hA -> hO -> hA -> hO(d_out)
  int nb = (N_NODES + 63) / 64;
  k_conv<<<nb, 256, 0, stream>>>(hA, hO, Wp, row, esrc, w1aP, b1a, w1bP, b1b, 1);
  k_conv<<<nb, 256, 0, stream>>>(hO, hA, Wp, row, esrc, w1aP, b1a, w1bP, b1b, 1);
  k_conv<<<nb, 256, 0, stream>>>(hA, hO, Wp, row, esrc, w1aP, b1a, w1bP, b1b, 0);
}

// Round 5
// 481.427 us; speedup vs baseline: 2.0887x; 2.0887x over previous
//
#include <hip/hip_runtime.h>
#include <hip/hip_bf16.h>

#define N_NODES 50000
#define N_EDGES 800000
#define HDIM 128
#define NCH 5
#define NB_SCAN ((N_NODES + 255) / 256)  // 196
#define CUTOFF 10.0f
#define WP_CAP 720000  // Wp row capacity; expected ~400k unmasked (guarded)

typedef float f4 __attribute__((ext_vector_type(4)));
typedef short bf8 __attribute__((ext_vector_type(8)));    // 8 bf16 = MFMA A/B frag
typedef float f32x4 __attribute__((ext_vector_type(4)));  // MFMA C/D frag

struct __align__(8) b16x4 { __hip_bfloat16 v[4]; };
struct __align__(16) b16x8 { __hip_bfloat16 v[8]; };

// ---------------- CSR build (split: unmasked / masked) ----------------

__global__ void k_count(const int* __restrict__ dst, const float* __restrict__ elen,
                        int* __restrict__ ucnt, int* __restrict__ mcnt) {
  int i = blockIdx.x * blockDim.x + threadIdx.x;
  if (i < N_EDGES) {
    int d = dst[i];
    if (elen[i] <= CUTOFF) atomicAdd(&ucnt[d], 1);
    else atomicAdd(&mcnt[d], 1);
  }
}

__global__ __launch_bounds__(256) void k_scan_local(const int* __restrict__ cnt,
                                                    int* __restrict__ row,
                                                    int* __restrict__ bsum) {
  __shared__ int buf[256];
  int b = blockIdx.x, tid = threadIdx.x, i = b * 256 + tid;
  int v = (i < N_NODES) ? cnt[i] : 0;
  buf[tid] = v;
  __syncthreads();
  for (int off = 1; off < 256; off <<= 1) {
    int t = (tid >= off) ? buf[tid - off] : 0;
    __syncthreads();
    buf[tid] += t;
    __syncthreads();
  }
  if (i < N_NODES) row[i] = buf[tid] - v;  // local exclusive
  if (tid == 255) bsum[b] = buf[255];
}

__global__ __launch_bounds__(256) void k_scan_top(const int* __restrict__ bsum,
                                                  int* __restrict__ boff) {
  __shared__ int buf[256];
  int tid = threadIdx.x;
  int v = (tid < NB_SCAN) ? bsum[tid] : 0;
  buf[tid] = v;
  __syncthreads();
  for (int off = 1; off < 256; off <<= 1) {
    int t = (tid >= off) ? buf[tid - off] : 0;
    __syncthreads();
    buf[tid] += t;
    __syncthreads();
  }
  if (tid < NB_SCAN) boff[tid] = buf[tid] - v;
  if (tid == 255) boff[NB_SCAN] = buf[255];  // total
}

// row/cur get +base (base = 0 for uCSR, = nUm for mCSR so mrow indexes esrc2 directly)
__global__ __launch_bounds__(256) void k_scan_add(int* __restrict__ row,
                                                  const int* __restrict__ boff,
                                                  int* __restrict__ cur,
                                                  const int* __restrict__ basep) {
  int b = blockIdx.x, tid = threadIdx.x, i = b * 256 + tid;
  int base = basep[0];
  if (i < N_NODES) {
    int r = row[i] + boff[b] + base;
    row[i] = r;
    cur[i] = r;
  }
  if (b == 0 && tid == 0) row[N_NODES] = boff[NB_SCAN] + base;
}

// unmasked edge -> uslot p: esrc2[p]=src, uedge[p]=edge id (for gate's attr gather)
// masked edge   -> mslot q (q >= nUm): esrc2[q]=src
__global__ void k_scatter(const int* __restrict__ src, const int* __restrict__ dst,
                          const float* __restrict__ elen, int* __restrict__ ucur,
                          int* __restrict__ mcur, int* __restrict__ esrc2,
                          int* __restrict__ uedge) {
  int i = blockIdx.x * blockDim.x + threadIdx.x;
  if (i < N_EDGES) {
    int d = dst[i];
    if (elen[i] <= CUTOFF) {
      int p = atomicAdd(&ucur[d], 1);
      esrc2[p] = src[i];
      if (p < WP_CAP) uedge[p] = i;
    } else {
      int q = atomicAdd(&mcur[d], 1);
      esrc2[q] = src[i];
    }
  }
}

// ---------------- weight repack for MFMA B-fragments ----------------
// wp[((jt*4+kk)*64 + l)*8 + j] = bf16( w[(kk*32 + (l>>4)*8 + j)*128 + jt*16 + (l&15)] )

__global__ __launch_bounds__(256) void k_repack(const float* __restrict__ w,
                                                __hip_bfloat16* __restrict__ wp) {
  int idx = blockIdx.x * 256 + threadIdx.x;
  int l = idx & 63;
  int f = idx >> 6;
  int kk = f & 3, jt = f >> 2;
  int col = jt * 16 + (l & 15);
  int kb = kk * 32 + (l >> 4) * 8;
  b16x8 o;
#pragma unroll
  for (int j = 0; j < 8; ++j) o.v[j] = __float2bfloat16(w[(kb + j) * HDIM + col]);
  *reinterpret_cast<b16x8*>(&wp[idx * 8]) = o;
}

// ---------------- f32 4x4-tile GEMM (node_emb only) --------

__device__ __forceinline__ void tile_gemm(const float (*in)[129],
                                          const float* __restrict__ wmat,
                                          const float* __restrict__ bias,
                                          int r4, int jb, float acc[4][4]) {
  f4 bv = *reinterpret_cast<const f4*>(&bias[jb]);
#pragma unroll
  for (int ii = 0; ii < 4; ++ii)
#pragma unroll
    for (int jj = 0; jj < 4; ++jj) acc[ii][jj] = bv[jj];
#pragma unroll 4
  for (int k = 0; k < HDIM; ++k) {
    f4 wv = *reinterpret_cast<const f4*>(&wmat[k * HDIM + jb]);
    float a0 = in[r4 + 0][k];
    float a1 = in[r4 + 1][k];
    float a2 = in[r4 + 2][k];
    float a3 = in[r4 + 3][k];
#pragma unroll
    for (int jj = 0; jj < 4; ++jj) {
      acc[0][jj] += a0 * wv[jj];
      acc[1][jj] += a1 * wv[jj];
      acc[2][jj] += a2 * wv[jj];
      acc[3][jj] += a3 * wv[jj];
    }
  }
}

// ---------------- node embedding -> h (f32) + hb (bf16 shadow) ----------------

__global__ __launch_bounds__(256) void k_node_emb(
    const float* __restrict__ z, const float* __restrict__ w0a,
    const float* __restrict__ b0a, const float* __restrict__ w0b,
    const float* __restrict__ b0b, float* __restrict__ h,
    __hip_bfloat16* __restrict__ hb) {
  __shared__ float zs[32][NCH];
  __shared__ float w0as[NCH][HDIM];
  __shared__ float hs[32][129];
  int tid = threadIdx.x;
  int r0 = blockIdx.x * 32;

  for (int i = tid; i < NCH * HDIM; i += 256) w0as[i / HDIM][i % HDIM] = w0a[i];
  for (int i = tid; i < 32 * NCH; i += 256) {
    int r = i / NCH, c = i % NCH;
    int gr = r0 + r;
    zs[r][c] = (gr < N_NODES) ? z[gr * NCH + c] : 0.f;
  }
  __syncthreads();

  for (int i = tid; i < 32 * HDIM; i += 256) {
    int j = i & (HDIM - 1), r = i >> 7;
    float a = b0a[j];
#pragma unroll
    for (int c = 0; c < NCH; ++c) a += zs[r][c] * w0as[c][j];
    hs[r][j] = fmaxf(a, 0.f);
  }
  __syncthreads();

  int cg = tid & 31, rg = tid >> 5;
  int jb = cg * 4, r4 = rg * 4;
  float acc[4][4];
  tile_gemm(hs, w0b, b0b, r4, jb, acc);

#pragma unroll
  for (int ii = 0; ii < 4; ++ii) {
    int gr = r0 + r4 + ii;
    if (gr < N_NODES) {
      f4 o = {acc[ii][0], acc[ii][1], acc[ii][2], acc[ii][3]};
      *reinterpret_cast<f4*>(&h[(size_t)gr * HDIM + jb]) = o;
      b16x4 ob;
#pragma unroll
      for (int jj = 0; jj < 4; ++jj) ob.v[jj] = __float2bfloat16(acc[ii][jj]);
      *reinterpret_cast<b16x4*>(&hb[(size_t)gr * HDIM + jb]) = ob;
    }
  }
}

// ---------------- edge gate via MFMA, processed in uCSR-slot order -------------
// Block b owns uslots [64b, 64b+64). attr gathered by uedge[slot]; Wp written
// contiguously at the slot — no pos/elist indirection at all.

#define SWZ(row, colByte) ((row) * 256 + ((colByte) ^ (((row) & 7) << 4)))

__global__ __launch_bounds__(256) void k_edge_gate_mfma(
    const float* __restrict__ attr, const __hip_bfloat16* __restrict__ w2aP,
    const float* __restrict__ b2a, const __hip_bfloat16* __restrict__ w2bP,
    const float* __restrict__ b2b, const int* __restrict__ uedge,
    const int* __restrict__ nUmPtr, __hip_bfloat16* __restrict__ Wp) {
  __shared__ char sA[64 * 256];  // 64 x 128 bf16, swizzled
  __shared__ char sH[64 * 256];
  __shared__ int sEid[64];
  const int tid = threadIdx.x;
  const int wv = tid >> 6, l = tid & 63;
  const int e0 = blockIdx.x * 64;
  const int nUm = min(nUmPtr[0], WP_CAP);
  if (e0 >= nUm) return;

  if (tid < 64) {
    int idx = e0 + tid;
    sEid[tid] = uedge[(idx < nUm) ? idx : (nUm - 1)];
  }
  __syncthreads();

  // stage attr rows (gathered by edge id) -> sA bf16
#pragma unroll
  for (int i = 0; i < 8; ++i) {
    int c = tid + i * 256;
    int row = c >> 5, col4 = (c & 31) * 4;
    f4 v = *reinterpret_cast<const f4*>(&attr[(size_t)sEid[row] * HDIM + col4]);
    b16x4 o;
    o.v[0] = __float2bfloat16(v[0]);
    o.v[1] = __float2bfloat16(v[1]);
    o.v[2] = __float2bfloat16(v[2]);
    o.v[3] = __float2bfloat16(v[3]);
    *reinterpret_cast<b16x4*>(&sA[SWZ(row, col4 * 2)]) = o;
  }

  bf8 B1[2][4], B2[2][4];
#pragma unroll
  for (int nt = 0; nt < 2; ++nt)
#pragma unroll
    for (int kk = 0; kk < 4; ++kk) {
      int f = (2 * wv + nt) * 4 + kk;
      B1[nt][kk] = *reinterpret_cast<const bf8*>(&w2aP[(f * 64 + l) * 8]);
      B2[nt][kk] = *reinterpret_cast<const bf8*>(&w2bP[(f * 64 + l) * 8]);
    }

  __syncthreads();

  // layer 1
  f32x4 acc[4][2];
  float bias[2];
#pragma unroll
  for (int nt = 0; nt < 2; ++nt) bias[nt] = b2a[(2 * wv + nt) * 16 + (l & 15)];
#pragma unroll
  for (int mt = 0; mt < 4; ++mt)
#pragma unroll
    for (int nt = 0; nt < 2; ++nt)
      acc[mt][nt] = (f32x4){bias[nt], bias[nt], bias[nt], bias[nt]};

#pragma unroll
  for (int kk = 0; kk < 4; ++kk)
#pragma unroll
    for (int mt = 0; mt < 4; ++mt) {
      int row = mt * 16 + (l & 15);
      int kByte = (kk * 32 + (l >> 4) * 8) * 2;
      bf8 a = *reinterpret_cast<const bf8*>(&sA[SWZ(row, kByte)]);
#pragma unroll
      for (int nt = 0; nt < 2; ++nt)
        acc[mt][nt] = __builtin_amdgcn_mfma_f32_16x16x32_bf16(a, B1[nt][kk],
                                                              acc[mt][nt], 0, 0, 0);
    }

#pragma unroll
  for (int mt = 0; mt < 4; ++mt)
#pragma unroll
    for (int nt = 0; nt < 2; ++nt) {
      int colb = ((2 * wv + nt) * 16 + (l & 15)) * 2;
#pragma unroll
      for (int i = 0; i < 4; ++i) {
        int row = mt * 16 + (l >> 4) * 4 + i;
        *reinterpret_cast<__hip_bfloat16*>(&sH[SWZ(row, colb)]) =
            __float2bfloat16(fmaxf(acc[mt][nt][i], 0.f));
      }
    }
  __syncthreads();

  // layer 2
#pragma unroll
  for (int nt = 0; nt < 2; ++nt) bias[nt] = b2b[(2 * wv + nt) * 16 + (l & 15)];
#pragma unroll
  for (int mt = 0; mt < 4; ++mt)
#pragma unroll
    for (int nt = 0; nt < 2; ++nt)
      acc[mt][nt] = (f32x4){bias[nt], bias[nt], bias[nt], bias[nt]};

#pragma unroll
  for (int kk = 0; kk < 4; ++kk)
#pragma unroll
    for (int mt = 0; mt < 4; ++mt) {
      int row = mt * 16 + (l & 15);
      int kByte = (kk * 32 + (l >> 4) * 8) * 2;
      bf8 a = *reinterpret_cast<const bf8*>(&sH[SWZ(row, kByte)]);
#pragma unroll
      for (int nt = 0; nt < 2; ++nt)
        acc[mt][nt] = __builtin_amdgcn_mfma_f32_16x16x32_bf16(a, B2[nt][kk],
                                                              acc[mt][nt], 0, 0, 0);
    }

  // write bf16 to sA (all listed edges pass the cutoff; no mask multiply)
#pragma unroll
  for (int mt = 0; mt < 4; ++mt)
#pragma unroll
    for (int nt = 0; nt < 2; ++nt) {
      int colb = ((2 * wv + nt) * 16 + (l & 15)) * 2;
#pragma unroll
      for (int i = 0; i < 4; ++i) {
        int row = mt * 16 + (l >> 4) * 4 + i;
        *reinterpret_cast<__hip_bfloat16*>(&sA[SWZ(row, colb)]) =
            __float2bfloat16(acc[mt][nt][i]);
      }
    }
  __syncthreads();

  // contiguous store: Wp rows e0..e0+63 (16 KB per block), tail-guarded
#pragma unroll
  for (int i = 0; i < 4; ++i) {
    int c = tid + i * 256;
    int row = c >> 4, colc = c & 15;
    if (e0 + row < nUm) {
      b16x8 v = *reinterpret_cast<const b16x8*>(&sA[SWZ(row, colc * 16)]);
      *reinterpret_cast<b16x8*>(&Wp[(size_t)(e0 + row) * HDIM + colc * 8]) = v;
    }
  }
}

// ---------------- aggregate: streamed Wp + bf16 h gathers -----------------------
// agg[n] = sum_{p in uCSR[n]} relu(hb[esrc2[p]] + Wp[p]) + sum_{q in mCSR[n]} relu(hb[esrc2[q]])

__global__ __launch_bounds__(256) void k_aggregate(
    const __hip_bfloat16* __restrict__ hb, const __hip_bfloat16* __restrict__ Wp,
    const int* __restrict__ urow, const int* __restrict__ mrow,
    const int* __restrict__ esrc2, float* __restrict__ agg) {
  int tid = threadIdx.x;
  int node = blockIdx.x * 8 + (tid >> 5);
  if (node >= N_NODES) return;
  int c4 = (tid & 31) * 4;
  f4 s = {0.f, 0.f, 0.f, 0.f};

  int ub = urow[node], ue = urow[node + 1];
  int ue1 = min(ue, WP_CAP);
  for (int p = ub; p < ue1; ++p) {
    int sr = esrc2[p];
    b16x4 hv = *reinterpret_cast<const b16x4*>(&hb[(size_t)sr * HDIM + c4]);
    b16x4 wv = *reinterpret_cast<const b16x4*>(&Wp[(size_t)p * HDIM + c4]);
#pragma unroll
    for (int q = 0; q < 4; ++q)
      s[q] += fmaxf(__bfloat162float(hv.v[q]) + __bfloat162float(wv.v[q]), 0.f);
  }
  for (int p = ue1; p < ue; ++p) {  // overflow guard path (never in practice)
    int sr = esrc2[p];
    b16x4 hv = *reinterpret_cast<const b16x4*>(&hb[(size_t)sr * HDIM + c4]);
#pragma unroll
    for (int q = 0; q < 4; ++q) s[q] += fmaxf(__bfloat162float(hv.v[q]), 0.f);
  }
  int mb = mrow[node], me = mrow[node + 1];
  for (int p = mb; p < me; ++p) {
    int sr = esrc2[p];
    b16x4 hv = *reinterpret_cast<const b16x4*>(&hb[(size_t)sr * HDIM + c4]);
#pragma unroll
    for (int q = 0; q < 4; ++q) s[q] += fmaxf(__bfloat162float(hv.v[q]), 0.f);
  }
  *reinterpret_cast<f4*>(&agg[(size_t)node * HDIM + c4]) = s;
}

// ---------------- update via MFMA: h += act(MLP1(agg + h)); refresh hb ---------

__global__ __launch_bounds__(256) void k_update_mfma(
    const float* __restrict__ agg, const __hip_bfloat16* __restrict__ w1aP,
    const float* __restrict__ b1a, const __hip_bfloat16* __restrict__ w1bP,
    const float* __restrict__ b1b, float* __restrict__ h,
    __hip_bfloat16* __restrict__ hb, int relu_out) {
  __shared__ char sA[64 * 256];  // 64 x 128 bf16 (agg+h), swizzled
  __shared__ char sH[64 * 256];
  const int tid = threadIdx.x;
  const int wv = tid >> 6, l = tid & 63;
  const int r0 = blockIdx.x * 64;

  // stage (agg + h) -> sA bf16
#pragma unroll
  for (int i = 0; i < 8; ++i) {
    int c = tid + i * 256;
    int row = c >> 5, col4 = (c & 31) * 4;
    int gr = r0 + row;
    f4 v = {0.f, 0.f, 0.f, 0.f};
    if (gr < N_NODES) {
      f4 a = *reinterpret_cast<const f4*>(&agg[(size_t)gr * HDIM + col4]);
      f4 hh = *reinterpret_cast<const f4*>(&h[(size_t)gr * HDIM + col4]);
      v = a + hh;
    }
    b16x4 o;
    o.v[0] = __float2bfloat16(v[0]);
    o.v[1] = __float2bfloat16(v[1]);
    o.v[2] = __float2bfloat16(v[2]);
    o.v[3] = __float2bfloat16(v[3]);
    *reinterpret_cast<b16x4*>(&sA[SWZ(row, col4 * 2)]) = o;
  }

  bf8 B1[2][4], B2[2][4];
#pragma unroll
  for (int nt = 0; nt < 2; ++nt)
#pragma unroll
    for (int kk = 0; kk < 4; ++kk) {
      int f = (2 * wv + nt) * 4 + kk;
      B1[nt][kk] = *reinterpret_cast<const bf8*>(&w1aP[(f * 64 + l) * 8]);
      B2[nt][kk] = *reinterpret_cast<const bf8*>(&w1bP[(f * 64 + l) * 8]);
    }

  __syncthreads();

  // layer 1
  f32x4 acc[4][2];
  float bias[2];
#pragma unroll
  for (int nt = 0; nt < 2; ++nt) bias[nt] = b1a[(2 * wv + nt) * 16 + (l & 15)];
#pragma unroll
  for (int mt = 0; mt < 4; ++mt)
#pragma unroll
    for (int nt = 0; nt < 2; ++nt)
      acc[mt][nt] = (f32x4){bias[nt], bias[nt], bias[nt], bias[nt]};

#pragma unroll
  for (int kk = 0; kk < 4; ++kk)
#pragma unroll
    for (int mt = 0; mt < 4; ++mt) {
      int rowi = mt * 16 + (l & 15);
      int kByte = (kk * 32 + (l >> 4) * 8) * 2;
      bf8 a = *reinterpret_cast<const bf8*>(&sA[SWZ(rowi, kByte)]);
#pragma unroll
      for (int nt = 0; nt < 2; ++nt)
        acc[mt][nt] = __builtin_amdgcn_mfma_f32_16x16x32_bf16(a, B1[nt][kk],
                                                              acc[mt][nt], 0, 0, 0);
    }

#pragma unroll
  for (int mt = 0; mt < 4; ++mt)
#pragma unroll
    for (int nt = 0; nt < 2; ++nt) {
      int colb = ((2 * wv + nt) * 16 + (l & 15)) * 2;
#pragma unroll
      for (int i = 0; i < 4; ++i) {
        int rowi = mt * 16 + (l >> 4) * 4 + i;
        *reinterpret_cast<__hip_bfloat16*>(&sH[SWZ(rowi, colb)]) =
            __float2bfloat16(fmaxf(acc[mt][nt][i], 0.f));
      }
    }
  __syncthreads();

  // layer 2
#pragma unroll
  for (int nt = 0; nt < 2; ++nt) bias[nt] = b1b[(2 * wv + nt) * 16 + (l & 15)];
#pragma unroll
  for (int mt = 0; mt < 4; ++mt)
#pragma unroll
    for (int nt = 0; nt < 2; ++nt)
      acc[mt][nt] = (f32x4){bias[nt], bias[nt], bias[nt], bias[nt]};

#pragma unroll
  for (int kk = 0; kk < 4; ++kk)
#pragma unroll
    for (int mt = 0; mt < 4; ++mt) {
      int rowi = mt * 16 + (l & 15);
      int kByte = (kk * 32 + (l >> 4) * 8) * 2;
      bf8 a = *reinterpret_cast<const bf8*>(&sH[SWZ(rowi, kByte)]);
#pragma unroll
      for (int nt = 0; nt < 2; ++nt)
        acc[mt][nt] = __builtin_amdgcn_mfma_f32_16x16x32_bf16(a, B2[nt][kk],
                                                              acc[mt][nt], 0, 0, 0);
    }

  // epilogue: h += act(out); hb = bf16(h)
#pragma unroll
  for (int mt = 0; mt < 4; ++mt)
#pragma unroll
    for (int nt = 0; nt < 2; ++nt) {
      int col = (2 * wv + nt) * 16 + (l & 15);
#pragma unroll
      for (int i = 0; i < 4; ++i) {
        int rowi = mt * 16 + (l >> 4) * 4 + i;
        int gr = r0 + rowi;
        if (gr < N_NODES) {
          float t = acc[mt][nt][i];
          if (relu_out) t = fmaxf(t, 0.f);
          size_t idx = (size_t)gr * HDIM + col;
          float nh = h[idx] + t;
          h[idx] = nh;
          hb[idx] = __float2bfloat16(nh);
        }
      }
    }
}

// ---------------- launch --------------------------------------------------------

extern "C" void kernel_launch(void* const* d_in, const int* in_sizes, int n_in,
                              void* d_out, int out_size, void* d_ws, size_t ws_size,
                              hipStream_t stream) {
  const float* z = (const float*)d_in[0];
  const int* ei = (const int*)d_in[1];
  const float* attr = (const float*)d_in[2];
  const float* elen = (const float*)d_in[3];
  const float* w0a = (const float*)d_in[4];
  const float* b0a = (const float*)d_in[5];
  const float* w0b = (const float*)d_in[6];
  const float* b0b = (const float*)d_in[7];
  const float* w1a = (const float*)d_in[8];
  const float* b1a = (const float*)d_in[9];
  const float* w1b = (const float*)d_in[10];
  const float* b1b = (const float*)d_in[11];
  const float* w2a = (const float*)d_in[12];
  const float* b2a = (const float*)d_in[13];
  const float* w2b = (const float*)d_in[14];
  const float* b2b = (const float*)d_in[15];

  float* h = (float*)d_out;  // f32 master copy of node features

  char* ws = (char*)d_ws;
  size_t off = 0;
  __hip_bfloat16* Wp = (__hip_bfloat16*)(ws + off);
  off += (size_t)WP_CAP * HDIM * 2;           // 184.3 MB
  float* agg = (float*)(ws + off);
  off += (size_t)N_NODES * HDIM * 4;          // 25.6 MB
  __hip_bfloat16* hb = (__hip_bfloat16*)(ws + off);
  off += (size_t)N_NODES * HDIM * 2;          // 12.8 MB
  int* esrc2 = (int*)(ws + off);
  off += (size_t)N_EDGES * 4;                 // 3.2 MB
  int* uedge = (int*)(ws + off);
  off += (size_t)WP_CAP * 4;                  // 2.88 MB
  int* urow = (int*)(ws + off);
  off += (size_t)(N_NODES + 64) * 4;
  int* mrow = (int*)(ws + off);
  off += (size_t)(N_NODES + 64) * 4;
  int* ucnt = (int*)(ws + off);               // [ucnt][mcnt][zeroI] one memset
  off += (size_t)N_NODES * 4;
  int* mcnt = (int*)(ws + off);
  off += (size_t)N_NODES * 4;
  int* zeroI = (int*)(ws + off);
  off += 64;
  int* ucur = (int*)(ws + off);
  off += (size_t)N_NODES * 4;
  int* mcur = (int*)(ws + off);
  off += (size_t)N_NODES * 4;
  int* ubsum = (int*)(ws + off);
  off += (size_t)(NB_SCAN + 8) * 4;
  int* uboff = (int*)(ws + off);
  off += (size_t)(NB_SCAN + 8) * 4;
  int* mbsum = (int*)(ws + off);
  off += (size_t)(NB_SCAN + 8) * 4;
  int* mboff = (int*)(ws + off);
  off += (size_t)(NB_SCAN + 8) * 4;
  __hip_bfloat16* w2aP = (__hip_bfloat16*)(ws + off);
  off += (size_t)HDIM * HDIM * 2;
  __hip_bfloat16* w2bP = (__hip_bfloat16*)(ws + off);
  off += (size_t)HDIM * HDIM * 2;
  __hip_bfloat16* w1aP = (__hip_bfloat16*)(ws + off);
  off += (size_t)HDIM * HDIM * 2;
  __hip_bfloat16* w1bP = (__hip_bfloat16*)(ws + off);
  off += (size_t)HDIM * HDIM * 2;  // total ~230 MB

  const int* src = ei;
  const int* dst = ei + N_EDGES;

  // split CSR build
  hipMemsetAsync(ucnt, 0, (size_t)(2 * N_NODES) * 4 + 64, stream);
  k_count<<<(N_EDGES + 255) / 256, 256, 0, stream>>>(dst, elen, ucnt, mcnt);
  k_scan_local<<<NB_SCAN, 256, 0, stream>>>(ucnt, urow, ubsum);
  k_scan_top<<<1, 256, 0, stream>>>(ubsum, uboff);
  k_scan_add<<<NB_SCAN, 256, 0, stream>>>(urow, uboff, ucur, zeroI);
  k_scan_local<<<NB_SCAN, 256, 0, stream>>>(mcnt, mrow, mbsum);
  k_scan_top<<<1, 256, 0, stream>>>(mbsum, mboff);
  k_scan_add<<<NB_SCAN, 256, 0, stream>>>(mrow, mboff, mcur, &uboff[NB_SCAN]);
  k_scatter<<<(N_EDGES + 255) / 256, 256, 0, stream>>>(src, dst, elen, ucur, mcur,
                                                       esrc2, uedge);

  // weight repacks
  k_repack<<<8, 256, 0, stream>>>(w2a, w2aP);
  k_repack<<<8, 256, 0, stream>>>(w2b, w2bP);
  k_repack<<<8, 256, 0, stream>>>(w1a, w1aP);
  k_repack<<<8, 256, 0, stream>>>(w1b, w1bP);

  // node embedding -> h (d_out) + hb
  k_node_emb<<<(N_NODES + 31) / 32, 256, 0, stream>>>(z, w0a, b0a, w0b, b0b, h, hb);

  // edge gate in uCSR-slot order (worst-case grid; blocks past nUm exit early)
  k_edge_gate_mfma<<<(N_EDGES + 63) / 64, 256, 0, stream>>>(
      attr, w2aP, b2a, w2bP, b2b, uedge, &urow[N_NODES], Wp);

  // convs (in-place h update; hb refreshed each conv)
  for (int conv = 0; conv < 3; ++conv) {
    k_aggregate<<<(N_NODES + 7) / 8, 256, 0, stream>>>(hb, Wp, urow, mrow, esrc2,
                                                       agg);
    k_update_mfma<<<(N_NODES + 63) / 64, 256, 0, stream>>>(
        agg, w1aP, b1a, w1bP, b1b, h, hb, conv < 2 ? 1 : 0);
  }
}

// Round 6
// 416.728 us; speedup vs baseline: 2.4130x; 1.1553x over previous
//
#include <hip/hip_runtime.h>
#include <hip/hip_bf16.h>

#define N_NODES 50000
#define N_EDGES 800000
#define HDIM 128
#define NCH 5
#define NB_SCAN ((N_NODES + 255) / 256)  // 196
#define CUTOFF 10.0f
#define WP_CAP 720000  // Wp row capacity; expected ~400k unmasked (guarded)

typedef float f4 __attribute__((ext_vector_type(4)));
typedef short bf8 __attribute__((ext_vector_type(8)));    // 8 bf16 = MFMA A/B frag
typedef short s8v __attribute__((ext_vector_type(8)));    // raw 8x bf16 bits
typedef float f32x4 __attribute__((ext_vector_type(4)));  // MFMA C/D frag

struct __align__(8) b16x4 { __hip_bfloat16 v[4]; };
struct __align__(16) b16x8 { __hip_bfloat16 v[8]; };

__device__ __forceinline__ float bf2f(short u) {
  return __uint_as_float(((unsigned)(unsigned short)u) << 16);
}

// ---------------- CSR build (split: unmasked / masked; single atomic pass) ------

__global__ void k_count(const int* __restrict__ dst, const float* __restrict__ elen,
                        int* __restrict__ ucnt, int* __restrict__ mcnt,
                        int* __restrict__ rank) {
  int i = blockIdx.x * blockDim.x + threadIdx.x;
  if (i < N_EDGES) {
    int d = dst[i];
    if (elen[i] <= CUTOFF) rank[i] = atomicAdd(&ucnt[d], 1);
    else rank[i] = atomicAdd(&mcnt[d], 1);
  }
}

__global__ __launch_bounds__(256) void k_scan_local(const int* __restrict__ cnt,
                                                    int* __restrict__ row,
                                                    int* __restrict__ bsum) {
  __shared__ int buf[256];
  int b = blockIdx.x, tid = threadIdx.x, i = b * 256 + tid;
  int v = (i < N_NODES) ? cnt[i] : 0;
  buf[tid] = v;
  __syncthreads();
  for (int off = 1; off < 256; off <<= 1) {
    int t = (tid >= off) ? buf[tid - off] : 0;
    __syncthreads();
    buf[tid] += t;
    __syncthreads();
  }
  if (i < N_NODES) row[i] = buf[tid] - v;  // local exclusive
  if (tid == 255) bsum[b] = buf[255];
}

__global__ __launch_bounds__(256) void k_scan_top(const int* __restrict__ bsum,
                                                  int* __restrict__ boff) {
  __shared__ int buf[256];
  int tid = threadIdx.x;
  int v = (tid < NB_SCAN) ? bsum[tid] : 0;
  buf[tid] = v;
  __syncthreads();
  for (int off = 1; off < 256; off <<= 1) {
    int t = (tid >= off) ? buf[tid - off] : 0;
    __syncthreads();
    buf[tid] += t;
    __syncthreads();
  }
  if (tid < NB_SCAN) boff[tid] = buf[tid] - v;
  if (tid == 255) boff[NB_SCAN] = buf[255];  // total
}

// row += boff + base (base = 0 for uCSR, = nUm for mCSR)
__global__ __launch_bounds__(256) void k_scan_add(int* __restrict__ row,
                                                  const int* __restrict__ boff,
                                                  const int* __restrict__ basep) {
  int b = blockIdx.x, tid = threadIdx.x, i = b * 256 + tid;
  int base = basep[0];
  if (i < N_NODES) row[i] += boff[b] + base;
  if (b == 0 && tid == 0) row[N_NODES] = boff[NB_SCAN] + base;
}

// atomic-free scatter: slot = row[dst] + rank
__global__ void k_scatter(const int* __restrict__ src, const int* __restrict__ dst,
                          const float* __restrict__ elen,
                          const int* __restrict__ urow, const int* __restrict__ mrow,
                          const int* __restrict__ rank, int* __restrict__ esrc2,
                          int* __restrict__ uedge) {
  int i = blockIdx.x * blockDim.x + threadIdx.x;
  if (i < N_EDGES) {
    int d = dst[i];
    if (elen[i] <= CUTOFF) {
      int p = urow[d] + rank[i];
      esrc2[p] = src[i];
      if (p < WP_CAP) uedge[p] = i;
    } else {
      int q = mrow[d] + rank[i];
      esrc2[q] = src[i];
    }
  }
}

// ---------------- weight repack for MFMA B-fragments ----------------
// wp[((jt*4+kk)*64 + l)*8 + j] = bf16( w[(kk*32 + (l>>4)*8 + j)*128 + jt*16 + (l&15)] )

__global__ __launch_bounds__(256) void k_repack(const float* __restrict__ w,
                                                __hip_bfloat16* __restrict__ wp) {
  int idx = blockIdx.x * 256 + threadIdx.x;
  int l = idx & 63;
  int f = idx >> 6;
  int kk = f & 3, jt = f >> 2;
  int col = jt * 16 + (l & 15);
  int kb = kk * 32 + (l >> 4) * 8;
  b16x8 o;
#pragma unroll
  for (int j = 0; j < 8; ++j) o.v[j] = __float2bfloat16(w[(kb + j) * HDIM + col]);
  *reinterpret_cast<b16x8*>(&wp[idx * 8]) = o;
}

// ---------------- f32 4x4-tile GEMM (node_emb only) --------

__device__ __forceinline__ void tile_gemm(const float (*in)[129],
                                          const float* __restrict__ wmat,
                                          const float* __restrict__ bias,
                                          int r4, int jb, float acc[4][4]) {
  f4 bv = *reinterpret_cast<const f4*>(&bias[jb]);
#pragma unroll
  for (int ii = 0; ii < 4; ++ii)
#pragma unroll
    for (int jj = 0; jj < 4; ++jj) acc[ii][jj] = bv[jj];
#pragma unroll 4
  for (int k = 0; k < HDIM; ++k) {
    f4 wv = *reinterpret_cast<const f4*>(&wmat[k * HDIM + jb]);
    float a0 = in[r4 + 0][k];
    float a1 = in[r4 + 1][k];
    float a2 = in[r4 + 2][k];
    float a3 = in[r4 + 3][k];
#pragma unroll
    for (int jj = 0; jj < 4; ++jj) {
      acc[0][jj] += a0 * wv[jj];
      acc[1][jj] += a1 * wv[jj];
      acc[2][jj] += a2 * wv[jj];
      acc[3][jj] += a3 * wv[jj];
    }
  }
}

// ---------------- node embedding -> h (f32) + hb (bf16 shadow) ----------------

__global__ __launch_bounds__(256) void k_node_emb(
    const float* __restrict__ z, const float* __restrict__ w0a,
    const float* __restrict__ b0a, const float* __restrict__ w0b,
    const float* __restrict__ b0b, float* __restrict__ h,
    __hip_bfloat16* __restrict__ hb) {
  __shared__ float zs[32][NCH];
  __shared__ float w0as[NCH][HDIM];
  __shared__ float hs[32][129];
  int tid = threadIdx.x;
  int r0 = blockIdx.x * 32;

  for (int i = tid; i < NCH * HDIM; i += 256) w0as[i / HDIM][i % HDIM] = w0a[i];
  for (int i = tid; i < 32 * NCH; i += 256) {
    int r = i / NCH, c = i % NCH;
    int gr = r0 + r;
    zs[r][c] = (gr < N_NODES) ? z[gr * NCH + c] : 0.f;
  }
  __syncthreads();

  for (int i = tid; i < 32 * HDIM; i += 256) {
    int j = i & (HDIM - 1), r = i >> 7;
    float a = b0a[j];
#pragma unroll
    for (int c = 0; c < NCH; ++c) a += zs[r][c] * w0as[c][j];
    hs[r][j] = fmaxf(a, 0.f);
  }
  __syncthreads();

  int cg = tid & 31, rg = tid >> 5;
  int jb = cg * 4, r4 = rg * 4;
  float acc[4][4];
  tile_gemm(hs, w0b, b0b, r4, jb, acc);

#pragma unroll
  for (int ii = 0; ii < 4; ++ii) {
    int gr = r0 + r4 + ii;
    if (gr < N_NODES) {
      f4 o = {acc[ii][0], acc[ii][1], acc[ii][2], acc[ii][3]};
      *reinterpret_cast<f4*>(&h[(size_t)gr * HDIM + jb]) = o;
      b16x4 ob;
#pragma unroll
      for (int jj = 0; jj < 4; ++jj) ob.v[jj] = __float2bfloat16(acc[ii][jj]);
      *reinterpret_cast<b16x4*>(&hb[(size_t)gr * HDIM + jb]) = ob;
    }
  }
}

// ---------------- edge gate via MFMA, uCSR-slot order; single LDS tile ---------
// Block b owns uslots [64b, 64b+64). sA serves input -> hidden -> output
// (extra syncthreads instead of a second 16KB buffer: 16.7KB LDS -> 8 blocks/CU).

#define SWZ(row, colByte) ((row) * 256 + ((colByte) ^ (((row) & 7) << 4)))

__global__ __launch_bounds__(256) void k_edge_gate_mfma(
    const float* __restrict__ attr, const __hip_bfloat16* __restrict__ w2aP,
    const float* __restrict__ b2a, const __hip_bfloat16* __restrict__ w2bP,
    const float* __restrict__ b2b, const int* __restrict__ uedge,
    const int* __restrict__ nUmPtr, __hip_bfloat16* __restrict__ Wp) {
  __shared__ char sA[64 * 256];  // 64 x 128 bf16, swizzled (reused 3x)
  __shared__ int sEid[64];
  const int tid = threadIdx.x;
  const int wv = tid >> 6, l = tid & 63;
  const int e0 = blockIdx.x * 64;
  const int nUm = min(nUmPtr[0], WP_CAP);
  if (e0 >= nUm) return;

  if (tid < 64) {
    int idx = e0 + tid;
    sEid[tid] = uedge[(idx < nUm) ? idx : (nUm - 1)];
  }
  __syncthreads();

  // stage attr rows (gathered by edge id) -> sA bf16
#pragma unroll
  for (int i = 0; i < 8; ++i) {
    int c = tid + i * 256;
    int row = c >> 5, col4 = (c & 31) * 4;
    f4 v = *reinterpret_cast<const f4*>(&attr[(size_t)sEid[row] * HDIM + col4]);
    b16x4 o;
    o.v[0] = __float2bfloat16(v[0]);
    o.v[1] = __float2bfloat16(v[1]);
    o.v[2] = __float2bfloat16(v[2]);
    o.v[3] = __float2bfloat16(v[3]);
    *reinterpret_cast<b16x4*>(&sA[SWZ(row, col4 * 2)]) = o;
  }

  bf8 B1[2][4], B2[2][4];
#pragma unroll
  for (int nt = 0; nt < 2; ++nt)
#pragma unroll
    for (int kk = 0; kk < 4; ++kk) {
      int f = (2 * wv + nt) * 4 + kk;
      B1[nt][kk] = *reinterpret_cast<const bf8*>(&w2aP[(f * 64 + l) * 8]);
      B2[nt][kk] = *reinterpret_cast<const bf8*>(&w2bP[(f * 64 + l) * 8]);
    }

  __syncthreads();

  // layer 1
  f32x4 acc[4][2];
  float bias[2];
#pragma unroll
  for (int nt = 0; nt < 2; ++nt) bias[nt] = b2a[(2 * wv + nt) * 16 + (l & 15)];
#pragma unroll
  for (int mt = 0; mt < 4; ++mt)
#pragma unroll
    for (int nt = 0; nt < 2; ++nt)
      acc[mt][nt] = (f32x4){bias[nt], bias[nt], bias[nt], bias[nt]};

#pragma unroll
  for (int kk = 0; kk < 4; ++kk)
#pragma unroll
    for (int mt = 0; mt < 4; ++mt) {
      int row = mt * 16 + (l & 15);
      int kByte = (kk * 32 + (l >> 4) * 8) * 2;
      bf8 a = *reinterpret_cast<const bf8*>(&sA[SWZ(row, kByte)]);
#pragma unroll
      for (int nt = 0; nt < 2; ++nt)
        acc[mt][nt] = __builtin_amdgcn_mfma_f32_16x16x32_bf16(a, B1[nt][kk],
                                                              acc[mt][nt], 0, 0, 0);
    }
  __syncthreads();  // all sA reads done; safe to overwrite

  // hidden = relu(acc) -> sA
#pragma unroll
  for (int mt = 0; mt < 4; ++mt)
#pragma unroll
    for (int nt = 0; nt < 2; ++nt) {
      int colb = ((2 * wv + nt) * 16 + (l & 15)) * 2;
#pragma unroll
      for (int i = 0; i < 4; ++i) {
        int row = mt * 16 + (l >> 4) * 4 + i;
        *reinterpret_cast<__hip_bfloat16*>(&sA[SWZ(row, colb)]) =
            __float2bfloat16(fmaxf(acc[mt][nt][i], 0.f));
      }
    }
  __syncthreads();

  // layer 2
#pragma unroll
  for (int nt = 0; nt < 2; ++nt) bias[nt] = b2b[(2 * wv + nt) * 16 + (l & 15)];
#pragma unroll
  for (int mt = 0; mt < 4; ++mt)
#pragma unroll
    for (int nt = 0; nt < 2; ++nt)
      acc[mt][nt] = (f32x4){bias[nt], bias[nt], bias[nt], bias[nt]};

#pragma unroll
  for (int kk = 0; kk < 4; ++kk)
#pragma unroll
    for (int mt = 0; mt < 4; ++mt) {
      int row = mt * 16 + (l & 15);
      int kByte = (kk * 32 + (l >> 4) * 8) * 2;
      bf8 a = *reinterpret_cast<const bf8*>(&sA[SWZ(row, kByte)]);
#pragma unroll
      for (int nt = 0; nt < 2; ++nt)
        acc[mt][nt] = __builtin_amdgcn_mfma_f32_16x16x32_bf16(a, B2[nt][kk],
                                                              acc[mt][nt], 0, 0, 0);
    }
  __syncthreads();  // all layer-2 sA reads done

  // output -> sA
#pragma unroll
  for (int mt = 0; mt < 4; ++mt)
#pragma unroll
    for (int nt = 0; nt < 2; ++nt) {
      int colb = ((2 * wv + nt) * 16 + (l & 15)) * 2;
#pragma unroll
      for (int i = 0; i < 4; ++i) {
        int row = mt * 16 + (l >> 4) * 4 + i;
        *reinterpret_cast<__hip_bfloat16*>(&sA[SWZ(row, colb)]) =
            __float2bfloat16(acc[mt][nt][i]);
      }
    }
  __syncthreads();

  // contiguous store: Wp rows e0..e0+63, tail-guarded
#pragma unroll
  for (int i = 0; i < 4; ++i) {
    int c = tid + i * 256;
    int row = c >> 4, colc = c & 15;
    if (e0 + row < nUm) {
      b16x8 v = *reinterpret_cast<const b16x8*>(&sA[SWZ(row, colc * 16)]);
      *reinterpret_cast<b16x8*>(&Wp[(size_t)(e0 + row) * HDIM + colc * 8]) = v;
    }
  }
}

// ---------------- aggregate: 16-lane groups, shfl-batched indices, 4-wide MLP --
// agg[n] = sum_{p in uCSR[n]} relu(hb[esrc2[p]] + Wp[p]) + sum_{q in mCSR[n]} relu(hb[esrc2[q]])

__global__ __launch_bounds__(256) void k_aggregate(
    const __hip_bfloat16* __restrict__ hb, const __hip_bfloat16* __restrict__ Wp,
    const int* __restrict__ urow, const int* __restrict__ mrow,
    const int* __restrict__ esrc2, float* __restrict__ agg) {
  int tid = threadIdx.x;
  int node = blockIdx.x * 16 + (tid >> 4);
  if (node >= N_NODES) return;
  const int lane16 = tid & 15;
  const int grpBase = tid & 48;  // group's base lane within the 64-lane wave
  const int c8 = lane16 * 8;

  float s[8];
#pragma unroll
  for (int q = 0; q < 8; ++q) s[q] = 0.f;

  // ---- unmasked edges: hb gather + Wp stream
  int ub = urow[node], ueFull = urow[node + 1];
  int ue = min(ueFull, WP_CAP);
  for (int p0 = ub; p0 < ue; p0 += 16) {
    int cnt = ue - p0;
    if (cnt > 16) cnt = 16;
    int idx = (lane16 < cnt) ? esrc2[p0 + lane16] : 0;
    for (int j = 0; j < cnt; j += 4) {
      s8v hv[4], wv[4];
#pragma unroll
      for (int t = 0; t < 4; ++t) {
        int sr = __shfl(idx, grpBase + j + t, 64);
        if (j + t < cnt) {
          hv[t] = *reinterpret_cast<const s8v*>(&hb[(size_t)sr * HDIM + c8]);
          wv[t] = *reinterpret_cast<const s8v*>(&Wp[(size_t)(p0 + j + t) * HDIM + c8]);
        } else {
          hv[t] = (s8v)0;
          wv[t] = (s8v)0;
        }
      }
#pragma unroll
      for (int t = 0; t < 4; ++t)
#pragma unroll
        for (int q = 0; q < 8; ++q)
          s[q] += fmaxf(bf2f(hv[t][q]) + bf2f(wv[t][q]), 0.f);
    }
  }
  for (int p = ue; p < ueFull; ++p) {  // WP_CAP overflow guard (never in practice)
    int sr = esrc2[p];
    s8v hv = *reinterpret_cast<const s8v*>(&hb[(size_t)sr * HDIM + c8]);
#pragma unroll
    for (int q = 0; q < 8; ++q) s[q] += fmaxf(bf2f(hv[q]), 0.f);
  }

  // ---- masked edges: relu(hb) only
  int mb = mrow[node], me = mrow[node + 1];
  for (int p0 = mb; p0 < me; p0 += 16) {
    int cnt = me - p0;
    if (cnt > 16) cnt = 16;
    int idx = (lane16 < cnt) ? esrc2[p0 + lane16] : 0;
    for (int j = 0; j < cnt; j += 4) {
      s8v hv[4];
#pragma unroll
      for (int t = 0; t < 4; ++t) {
        int sr = __shfl(idx, grpBase + j + t, 64);
        if (j + t < cnt)
          hv[t] = *reinterpret_cast<const s8v*>(&hb[(size_t)sr * HDIM + c8]);
        else
          hv[t] = (s8v)0;
      }
#pragma unroll
      for (int t = 0; t < 4; ++t)
#pragma unroll
        for (int q = 0; q < 8; ++q) s[q] += fmaxf(bf2f(hv[t][q]), 0.f);
    }
  }

  f4 o0 = {s[0], s[1], s[2], s[3]};
  f4 o1 = {s[4], s[5], s[6], s[7]};
  *reinterpret_cast<f4*>(&agg[(size_t)node * HDIM + c8]) = o0;
  *reinterpret_cast<f4*>(&agg[(size_t)node * HDIM + c8 + 4]) = o1;
}

// ---------------- update via MFMA: h += act(MLP1(agg + h)); refresh hb ---------
// Single LDS tile (16.4KB) -> 8 blocks/CU.

__global__ __launch_bounds__(256) void k_update_mfma(
    const float* __restrict__ agg, const __hip_bfloat16* __restrict__ w1aP,
    const float* __restrict__ b1a, const __hip_bfloat16* __restrict__ w1bP,
    const float* __restrict__ b1b, float* __restrict__ h,
    __hip_bfloat16* __restrict__ hb, int relu_out) {
  __shared__ char sA[64 * 256];  // 64 x 128 bf16, swizzled (reused)
  const int tid = threadIdx.x;
  const int wv = tid >> 6, l = tid & 63;
  const int r0 = blockIdx.x * 64;

  // stage (agg + h) -> sA bf16
#pragma unroll
  for (int i = 0; i < 8; ++i) {
    int c = tid + i * 256;
    int row = c >> 5, col4 = (c & 31) * 4;
    int gr = r0 + row;
    f4 v = {0.f, 0.f, 0.f, 0.f};
    if (gr < N_NODES) {
      f4 a = *reinterpret_cast<const f4*>(&agg[(size_t)gr * HDIM + col4]);
      f4 hh = *reinterpret_cast<const f4*>(&h[(size_t)gr * HDIM + col4]);
      v = a + hh;
    }
    b16x4 o;
    o.v[0] = __float2bfloat16(v[0]);
    o.v[1] = __float2bfloat16(v[1]);
    o.v[2] = __float2bfloat16(v[2]);
    o.v[3] = __float2bfloat16(v[3]);
    *reinterpret_cast<b16x4*>(&sA[SWZ(row, col4 * 2)]) = o;
  }

  bf8 B1[2][4], B2[2][4];
#pragma unroll
  for (int nt = 0; nt < 2; ++nt)
#pragma unroll
    for (int kk = 0; kk < 4; ++kk) {
      int f = (2 * wv + nt) * 4 + kk;
      B1[nt][kk] = *reinterpret_cast<const bf8*>(&w1aP[(f * 64 + l) * 8]);
      B2[nt][kk] = *reinterpret_cast<const bf8*>(&w1bP[(f * 64 + l) * 8]);
    }

  __syncthreads();

  // layer 1
  f32x4 acc[4][2];
  float bias[2];
#pragma unroll
  for (int nt = 0; nt < 2; ++nt) bias[nt] = b1a[(2 * wv + nt) * 16 + (l & 15)];
#pragma unroll
  for (int mt = 0; mt < 4; ++mt)
#pragma unroll
    for (int nt = 0; nt < 2; ++nt)
      acc[mt][nt] = (f32x4){bias[nt], bias[nt], bias[nt], bias[nt]};

#pragma unroll
  for (int kk = 0; kk < 4; ++kk)
#pragma unroll
    for (int mt = 0; mt < 4; ++mt) {
      int rowi = mt * 16 + (l & 15);
      int kByte = (kk * 32 + (l >> 4) * 8) * 2;
      bf8 a = *reinterpret_cast<const bf8*>(&sA[SWZ(rowi, kByte)]);
#pragma unroll
      for (int nt = 0; nt < 2; ++nt)
        acc[mt][nt] = __builtin_amdgcn_mfma_f32_16x16x32_bf16(a, B1[nt][kk],
                                                              acc[mt][nt], 0, 0, 0);
    }
  __syncthreads();  // all sA reads done

  // hidden -> sA
#pragma unroll
  for (int mt = 0; mt < 4; ++mt)
#pragma unroll
    for (int nt = 0; nt < 2; ++nt) {
      int colb = ((2 * wv + nt) * 16 + (l & 15)) * 2;
#pragma unroll
      for (int i = 0; i < 4; ++i) {
        int rowi = mt * 16 + (l >> 4) * 4 + i;
        *reinterpret_cast<__hip_bfloat16*>(&sA[SWZ(rowi, colb)]) =
            __float2bfloat16(fmaxf(acc[mt][nt][i], 0.f));
      }
    }
  __syncthreads();

  // layer 2
#pragma unroll
  for (int nt = 0; nt < 2; ++nt) bias[nt] = b1b[(2 * wv + nt) * 16 + (l & 15)];
#pragma unroll
  for (int mt = 0; mt < 4; ++mt)
#pragma unroll
    for (int nt = 0; nt < 2; ++nt)
      acc[mt][nt] = (f32x4){bias[nt], bias[nt], bias[nt], bias[nt]};

#pragma unroll
  for (int kk = 0; kk < 4; ++kk)
#pragma unroll
    for (int mt = 0; mt < 4; ++mt) {
      int rowi = mt * 16 + (l & 15);
      int kByte = (kk * 32 + (l >> 4) * 8) * 2;
      bf8 a = *reinterpret_cast<const bf8*>(&sA[SWZ(rowi, kByte)]);
#pragma unroll
      for (int nt = 0; nt < 2; ++nt)
        acc[mt][nt] = __builtin_amdgcn_mfma_f32_16x16x32_bf16(a, B2[nt][kk],
                                                              acc[mt][nt], 0, 0, 0);
    }

  // epilogue: h += act(out); hb = bf16(h)
#pragma unroll
  for (int mt = 0; mt < 4; ++mt)
#pragma unroll
    for (int nt = 0; nt < 2; ++nt) {
      int col = (2 * wv + nt) * 16 + (l & 15);
#pragma unroll
      for (int i = 0; i < 4; ++i) {
        int rowi = mt * 16 + (l >> 4) * 4 + i;
        int gr = r0 + rowi;
        if (gr < N_NODES) {
          float t = acc[mt][nt][i];
          if (relu_out) t = fmaxf(t, 0.f);
          size_t idx = (size_t)gr * HDIM + col;
          float nh = h[idx] + t;
          h[idx] = nh;
          hb[idx] = __float2bfloat16(nh);
        }
      }
    }
}

// ---------------- launch --------------------------------------------------------

extern "C" void kernel_launch(void* const* d_in, const int* in_sizes, int n_in,
                              void* d_out, int out_size, void* d_ws, size_t ws_size,
                              hipStream_t stream) {
  const float* z = (const float*)d_in[0];
  const int* ei = (const int*)d_in[1];
  const float* attr = (const float*)d_in[2];
  const float* elen = (const float*)d_in[3];
  const float* w0a = (const float*)d_in[4];
  const float* b0a = (const float*)d_in[5];
  const float* w0b = (const float*)d_in[6];
  const float* b0b = (const float*)d_in[7];
  const float* w1a = (const float*)d_in[8];
  const float* b1a = (const float*)d_in[9];
  const float* w1b = (const float*)d_in[10];
  const float* b1b = (const float*)d_in[11];
  const float* w2a = (const float*)d_in[12];
  const float* b2a = (const float*)d_in[13];
  const float* w2b = (const float*)d_in[14];
  const float* b2b = (const float*)d_in[15];

  float* h = (float*)d_out;  // f32 master copy of node features

  char* ws = (char*)d_ws;
  size_t off = 0;
  __hip_bfloat16* Wp = (__hip_bfloat16*)(ws + off);
  off += (size_t)WP_CAP * HDIM * 2;           // 184.3 MB
  float* agg = (float*)(ws + off);
  off += (size_t)N_NODES * HDIM * 4;          // 25.6 MB
  __hip_bfloat16* hb = (__hip_bfloat16*)(ws + off);
  off += (size_t)N_NODES * HDIM * 2;          // 12.8 MB
  int* esrc2 = (int*)(ws + off);
  off += (size_t)N_EDGES * 4;                 // 3.2 MB
  int* uedge = (int*)(ws + off);
  off += (size_t)WP_CAP * 4;                  // 2.88 MB
  int* rank = (int*)(ws + off);
  off += (size_t)N_EDGES * 4;                 // 3.2 MB
  int* urow = (int*)(ws + off);
  off += (size_t)(N_NODES + 64) * 4;
  int* mrow = (int*)(ws + off);
  off += (size_t)(N_NODES + 64) * 4;
  int* ucnt = (int*)(ws + off);               // [ucnt][mcnt][zeroI] one memset
  off += (size_t)N_NODES * 4;
  int* mcnt = (int*)(ws + off);
  off += (size_t)N_NODES * 4;
  int* zeroI = (int*)(ws + off);
  off += 64;
  int* ubsum = (int*)(ws + off);
  off += (size_t)(NB_SCAN + 8) * 4;
  int* uboff = (int*)(ws + off);
  off += (size_t)(NB_SCAN + 8) * 4;
  int* mbsum = (int*)(ws + off);
  off += (size_t)(NB_SCAN + 8) * 4;
  int* mboff = (int*)(ws + off);
  off += (size_t)(NB_SCAN + 8) * 4;
  __hip_bfloat16* w2aP = (__hip_bfloat16*)(ws + off);
  off += (size_t)HDIM * HDIM * 2;
  __hip_bfloat16* w2bP = (__hip_bfloat16*)(ws + off);
  off += (size_t)HDIM * HDIM * 2;
  __hip_bfloat16* w1aP = (__hip_bfloat16*)(ws + off);
  off += (size_t)HDIM * HDIM * 2;
  __hip_bfloat16* w1bP = (__hip_bfloat16*)(ws + off);
  off += (size_t)HDIM * HDIM * 2;  // total ~233 MB

  const int* src = ei;
  const int* dst = ei + N_EDGES;

  // split CSR build (single atomic pass)
  hipMemsetAsync(ucnt, 0, (size_t)(2 * N_NODES) * 4 + 64, stream);
  k_count<<<(N_EDGES + 255) / 256, 256, 0, stream>>>(dst, elen, ucnt, mcnt, rank);
  k_scan_local<<<NB_SCAN, 256, 0, stream>>>(ucnt, urow, ubsum);
  k_scan_top<<<1, 256, 0, stream>>>(ubsum, uboff);
  k_scan_add<<<NB_SCAN, 256, 0, stream>>>(urow, uboff, zeroI);
  k_scan_local<<<NB_SCAN, 256, 0, stream>>>(mcnt, mrow, mbsum);
  k_scan_top<<<1, 256, 0, stream>>>(mbsum, mboff);
  k_scan_add<<<NB_SCAN, 256, 0, stream>>>(mrow, mboff, &uboff[NB_SCAN]);
  k_scatter<<<(N_EDGES + 255) / 256, 256, 0, stream>>>(src, dst, elen, urow, mrow,
                                                       rank, esrc2, uedge);

  // weight repacks
  k_repack<<<8, 256, 0, stream>>>(w2a, w2aP);
  k_repack<<<8, 256, 0, stream>>>(w2b, w2bP);
  k_repack<<<8, 256, 0, stream>>>(w1a, w1aP);
  k_repack<<<8, 256, 0, stream>>>(w1b, w1bP);

  // node embedding -> h (d_out) + hb
  k_node_emb<<<(N_NODES + 31) / 32, 256, 0, stream>>>(z, w0a, b0a, w0b, b0b, h, hb);

  // edge gate in uCSR-slot order (worst-case grid; blocks past nUm exit early)
  k_edge_gate_mfma<<<(N_EDGES + 63) / 64, 256, 0, stream>>>(
      attr, w2aP, b2a, w2bP, b2b, uedge, &urow[N_NODES], Wp);

  // convs (in-place h update; hb refreshed each conv)
  for (int conv = 0; conv < 3; ++conv) {
    k_aggregate<<<(N_NODES + 15) / 16, 256, 0, stream>>>(hb, Wp, urow, mrow, esrc2,
                                                         agg);
    k_update_mfma<<<(N_NODES + 63) / 64, 256, 0, stream>>>(
        agg, w1aP, b1a, w1bP, b1b, h, hb, conv < 2 ? 1 : 0);
  }
}